// Round 2
// baseline (900.699 us; speedup 1.0000x reference)
//
#include <hip/hip_runtime.h>
#include <hip/hip_bf16.h>
#include <math.h>

#define N_NODES 50000
#define N_EDGES 1600000
#define H 64
#define G_GRAPHS 512
#define C_CLS 2
#define BN_EPS 1e-5f
#define NBUCK 196           // buckets of 256 nodes: dst>>8 in [0,196)
#define BUCKCAP 16384
#define E4 (N_EDGES / 4)    // 400000
#define SCHUNKS ((E4 + 511) / 512)        // 782 scatter chunks
#define XCHUNKS ((N_NODES + 255) / 256)   // 196 x-pack chunks
#define P0_UNITS (SCHUNKS + 5 + XCHUNKS)  // 983
#define NGROUP (N_NODES / 16)             // 3125
#define IOP 72              // padded LDS row stride (bf16)
#define GRID 768            // co-resident: launch_bounds(256,4) -> 4 blk/CU * 256 CU = 1024 >= 768

typedef __attribute__((ext_vector_type(8))) short short8;
typedef __attribute__((ext_vector_type(4))) float floatx4;

__device__ __forceinline__ float bflo(unsigned int u) { return __uint_as_float(u << 16); }
__device__ __forceinline__ float bfhi(unsigned int u) { return __uint_as_float(u & 0xffff0000u); }
__device__ __forceinline__ unsigned int bf16_rne(float f) {
    unsigned int u = __float_as_uint(f);
    u += 0x7fffu + ((u >> 16) & 1u);
    return u >> 16;
}

#define RED3(A) { A += __shfl_xor(A, 8); A += __shfl_xor(A, 16); A += __shfl_xor(A, 32); }
#define RED6(A) { A += __shfl_xor(A, 1); A += __shfl_xor(A, 2); A += __shfl_xor(A, 4); \
                  A += __shfl_xor(A, 8); A += __shfl_xor(A, 16); A += __shfl_xor(A, 32); }

// device-scope grid barrier: bar[0]=counter, bar[1]=generation (memset to 0 per launch).
// Spin MUST use agent-scope atomic loads (plain/volatile loads can spin forever on a
// stale non-coherent per-XCD L2 line). threadfence = release(wb) / acquire(inv).
__device__ __forceinline__ void gbar(int* bar) {
    __syncthreads();
    if (threadIdx.x == 0) {
        __threadfence();
        int g = __hip_atomic_load(&bar[1], __ATOMIC_RELAXED, __HIP_MEMORY_SCOPE_AGENT);
        int a = __hip_atomic_fetch_add(&bar[0], 1, __ATOMIC_ACQ_REL, __HIP_MEMORY_SCOPE_AGENT);
        if (a == GRID - 1) {
            __hip_atomic_store(&bar[0], 0, __ATOMIC_RELAXED, __HIP_MEMORY_SCOPE_AGENT);
            __hip_atomic_store(&bar[1], g + 1, __ATOMIC_RELEASE, __HIP_MEMORY_SCOPE_AGENT);
        } else {
            while (__hip_atomic_load(&bar[1], __ATOMIC_RELAXED, __HIP_MEMORY_SCOPE_AGENT) == g)
                __builtin_amdgcn_s_sleep(1);
        }
        __threadfence();
    }
    __syncthreads();
}

#define ACCV(R) { \
    a0 += bflo(R.x); a1 += bfhi(R.x); a2 += bflo(R.y); a3 += bfhi(R.y); \
    a4 += bflo(R.z); a5 += bfhi(R.z); a6 += bflo(R.w); a7 += bfhi(R.w); }

// ---- one 16-node group for layers 2/3: gather (4 nodes/wave, 4-deep) + 2-GEMM MLP ----
__device__ __forceinline__ void gin_group(
    int nodebase, int wave, int j, int quad, int l15, int jj,
    const char* hb, const int* __restrict__ row_start, const int* __restrict__ edge_src,
    short8 wb10, short8 wb11, short8 wb20, short8 wb21,
    float sc, float sh, float bb1, float bb2,
    unsigned short* s_xs, unsigned short* s_mid, int* s_bat,
    const int* __restrict__ batch, float* __restrict__ poolcol,
    __hip_bfloat16* __restrict__ hout) {
    int o = j >> 3, jo = j & 7;
    if (wave == 0 && j < 16) s_bat[j] = batch[nodebase + j];

    // phase A: each wave gathers 4 nodes (octet scheme, 4 loads in flight)
    for (int q = 0; q < 4; q++) {
        int nl = wave * 4 + q;
        int node = nodebase + nl;
        int rs = row_start[node], re = row_start[node + 1];
        int cntv = re - rs;
        float a0 = 0.f, a1 = 0.f, a2 = 0.f, a3 = 0.f, a4 = 0.f, a5 = 0.f, a6 = 0.f, a7 = 0.f;
        for (int base = 0; base < cntv; base += 64) {
            int idx = rs + base + j;
            int sv = (idx < re) ? edge_src[idx] : 0;
            int lim = min(64, cntv - base);
#pragma unroll
            for (int i = 0; i < 64; i += 32) {
                if (i >= lim) break;
                int r0 = i + o, r1 = i + 8 + o, r2 = i + 16 + o, r3 = i + 24 + o;
                int s0 = __shfl(sv, r0);
                int s1 = __shfl(sv, r1);
                int s2 = __shfl(sv, r2);
                int s3 = __shfl(sv, r3);
                uint4 R0 = *(const uint4*)(hb + (size_t)s0 * 128 + jo * 16);
                uint4 R1 = *(const uint4*)(hb + (size_t)s1 * 128 + jo * 16);
                uint4 R2 = *(const uint4*)(hb + (size_t)s2 * 128 + jo * 16);
                uint4 R3 = *(const uint4*)(hb + (size_t)s3 * 128 + jo * 16);
                if (r0 < lim) ACCV(R0)
                if (r1 < lim) ACCV(R1)
                if (r2 < lim) ACCV(R2)
                if (r3 < lim) ACCV(R3)
            }
        }
        RED3(a0) RED3(a1) RED3(a2) RED3(a3) RED3(a4) RED3(a5) RED3(a6) RED3(a7)
        if (o == 0) {
            uint4 raw = *(const uint4*)(hb + (size_t)node * 128 + jo * 16);
            a0 += bflo(raw.x); a1 += bfhi(raw.x);
            a2 += bflo(raw.y); a3 += bfhi(raw.y);
            a4 += bflo(raw.z); a5 += bfhi(raw.z);
            a6 += bflo(raw.w); a7 += bfhi(raw.w);
            uint4 ov;
            ov.x = bf16_rne(a0) | (bf16_rne(a1) << 16);
            ov.y = bf16_rne(a2) | (bf16_rne(a3) << 16);
            ov.z = bf16_rne(a4) | (bf16_rne(a5) << 16);
            ov.w = bf16_rne(a6) | (bf16_rne(a7) << 16);
            *(uint4*)&s_xs[nl * IOP + jo * 8] = ov;
        }
    }
    __syncthreads();

    // GEMM1 (jt = wave): mid = relu(bn(xs @ w1 + b1))
    {
        short8 A0 = *(const short8*)&s_xs[l15 * IOP + quad * 8];
        short8 A1 = *(const short8*)&s_xs[l15 * IOP + quad * 8 + 32];
        floatx4 c = {0.f, 0.f, 0.f, 0.f};
        c = __builtin_amdgcn_mfma_f32_16x16x32_bf16(A0, wb10, c, 0, 0, 0);
        c = __builtin_amdgcn_mfma_f32_16x16x32_bf16(A1, wb11, c, 0, 0, 0);
#pragma unroll
        for (int r = 0; r < 4; r++) {
            float v = (c[r] + bb1) * sc + sh;
            v = fmaxf(v, 0.f);
            s_mid[(quad * 4 + r) * IOP + jj] = (unsigned short)bf16_rne(v);
        }
    }
    __syncthreads();

    // GEMM2 (jt = wave): out = relu(mid @ w2 + b2); pool atomics
    {
        short8 M0 = *(const short8*)&s_mid[l15 * IOP + quad * 8];
        short8 M1 = *(const short8*)&s_mid[l15 * IOP + quad * 8 + 32];
        floatx4 c = {0.f, 0.f, 0.f, 0.f};
        c = __builtin_amdgcn_mfma_f32_16x16x32_bf16(M0, wb20, c, 0, 0, 0);
        c = __builtin_amdgcn_mfma_f32_16x16x32_bf16(M1, wb21, c, 0, 0, 0);
        float vv[4];
#pragma unroll
        for (int r = 0; r < 4; r++) {
            vv[r] = fmaxf(c[r] + bb2, 0.f);
            s_xs[(quad * 4 + r) * IOP + jj] = (unsigned short)bf16_rne(vv[r]);
        }
        int bq0 = s_bat[quad * 4], bq3 = s_bat[quad * 4 + 3];
        if (bq0 == bq3) {
            atomicAdd(&poolcol[bq0 * 192 + jj], (vv[0] + vv[1]) + (vv[2] + vv[3]));
        } else {
            atomicAdd(&poolcol[s_bat[quad * 4 + 0] * 192 + jj], vv[0]);
            atomicAdd(&poolcol[s_bat[quad * 4 + 1] * 192 + jj], vv[1]);
            atomicAdd(&poolcol[s_bat[quad * 4 + 2] * 192 + jj], vv[2]);
            atomicAdd(&poolcol[s_bat[quad * 4 + 3] * 192 + jj], vv[3]);
        }
    }
    __syncthreads();

    // store: wave w stores rows w*4 .. w*4+3 (32 lanes x 16B, contiguous 512B per wave)
    if (j < 32) {
        int r = wave * 4 + (j >> 3), ch = j & 7;
        short8 v = *(const short8*)&s_xs[r * IOP + ch * 8];
        *(short8*)((unsigned short*)hout + (size_t)(nodebase + r) * H + ch * 8) = v;
    }
    __syncthreads();
}

// ---- one 16-node group for layer 1 ----
__device__ __forceinline__ void gin1_group(
    int nodebase, int wave, int j, int quad, int l15, int jj,
    const float* __restrict__ x, const uint2* __restrict__ xb,
    const int* __restrict__ row_start, const int* __restrict__ edge_src,
    float wj0, float wj1, float wj2, float sc1, float sh1, float bj,
    short8 wb20, short8 wb21, float bb2,
    unsigned short* s_xs, unsigned short* s_mid, int* s_bat,
    const int* __restrict__ batch, float* __restrict__ poolcol,
    __hip_bfloat16* __restrict__ hout) {
    if (wave == 0 && j < 16) s_bat[j] = batch[nodebase + j];

    // phase A: gather 3-feature sums, lin1+bn+relu per channel j
    for (int q = 0; q < 4; q++) {
        int nl = wave * 4 + q;
        int node = nodebase + nl;
        int rs = row_start[node], re = row_start[node + 1];
        float a0 = 0.f, a1 = 0.f, a2 = 0.f;
        for (int t2 = rs + j; t2 < re; t2 += 64) {
            uint2 p = xb[edge_src[t2]];
            a0 += bflo(p.x); a1 += bfhi(p.x); a2 += bflo(p.y);
        }
        RED6(a0) RED6(a1) RED6(a2)
        float in0 = a0 + x[node * 3 + 0];
        float in1 = a1 + x[node * 3 + 1];
        float in2 = a2 + x[node * 3 + 2];
        float m = bj + in0 * wj0 + in1 * wj1 + in2 * wj2;
        m = fmaxf(m * sc1 + sh1, 0.f);
        s_mid[nl * IOP + j] = (unsigned short)bf16_rne(m);
    }
    __syncthreads();

    // GEMM2 (jt = wave)
    {
        short8 M0 = *(const short8*)&s_mid[l15 * IOP + quad * 8];
        short8 M1 = *(const short8*)&s_mid[l15 * IOP + quad * 8 + 32];
        floatx4 c = {0.f, 0.f, 0.f, 0.f};
        c = __builtin_amdgcn_mfma_f32_16x16x32_bf16(M0, wb20, c, 0, 0, 0);
        c = __builtin_amdgcn_mfma_f32_16x16x32_bf16(M1, wb21, c, 0, 0, 0);
        float vv[4];
#pragma unroll
        for (int r = 0; r < 4; r++) {
            vv[r] = fmaxf(c[r] + bb2, 0.f);
            s_xs[(quad * 4 + r) * IOP + jj] = (unsigned short)bf16_rne(vv[r]);
        }
        int bq0 = s_bat[quad * 4], bq3 = s_bat[quad * 4 + 3];
        if (bq0 == bq3) {
            atomicAdd(&poolcol[bq0 * 192 + jj], (vv[0] + vv[1]) + (vv[2] + vv[3]));
        } else {
            atomicAdd(&poolcol[s_bat[quad * 4 + 0] * 192 + jj], vv[0]);
            atomicAdd(&poolcol[s_bat[quad * 4 + 1] * 192 + jj], vv[1]);
            atomicAdd(&poolcol[s_bat[quad * 4 + 2] * 192 + jj], vv[2]);
            atomicAdd(&poolcol[s_bat[quad * 4 + 3] * 192 + jj], vv[3]);
        }
    }
    __syncthreads();

    if (j < 32) {
        int r = wave * 4 + (j >> 3), ch = j & 7;
        short8 v = *(const short8*)&s_xs[r * IOP + ch * 8];
        *(short8*)((unsigned short*)hout + (size_t)(nodebase + r) * H + ch * 8) = v;
    }
    __syncthreads();
}

// ---------------- the mega kernel: everything in one dispatch ----------------
__global__ __launch_bounds__(256, 4) void mega_kernel(
    const float* __restrict__ x,
    const float* __restrict__ w1_0, const float* __restrict__ b1_0,
    const float* __restrict__ g_0, const float* __restrict__ bb_0,
    const float* __restrict__ m_0, const float* __restrict__ v_0,
    const float* __restrict__ w2_0f, const float* __restrict__ b2_0,
    const float* __restrict__ w1_1f, const float* __restrict__ b1_1,
    const float* __restrict__ g_1, const float* __restrict__ bb_1,
    const float* __restrict__ m_1, const float* __restrict__ v_1,
    const float* __restrict__ w2_1f, const float* __restrict__ b2_1,
    const float* __restrict__ w1_2f, const float* __restrict__ b1_2,
    const float* __restrict__ g_2, const float* __restrict__ bb_2,
    const float* __restrict__ m_2, const float* __restrict__ v_2,
    const float* __restrict__ w2_2f, const float* __restrict__ b2_2,
    const float* __restrict__ lin1_w, const float* __restrict__ lin1_b,
    const float* __restrict__ lin2_w, const float* __restrict__ lin2_b,
    const int* __restrict__ esrc, const int* __restrict__ edst,
    const int* __restrict__ batch,
    int* __restrict__ edge_src, int* __restrict__ gpacked, int* __restrict__ gcnt,
    int* bar, float* __restrict__ pool, int* __restrict__ row_start,
    unsigned short* __restrict__ wt, uint2* __restrict__ xb,
    __hip_bfloat16* __restrict__ h1, __hip_bfloat16* __restrict__ h2,
    __hip_bfloat16* __restrict__ h3, float* __restrict__ out) {
    __shared__ int s_ia[256];
    __shared__ int s_ib[256];
    __shared__ unsigned short s_xs[16 * IOP];
    __shared__ unsigned short s_mid[16 * IOP];
    __shared__ int s_bat[16];
    __shared__ float s_hr[192];
    __shared__ float s_hm[192];
    __shared__ float s_z[C_CLS];

    int t = threadIdx.x;
    int wave = t >> 6, j = t & 63;
    int quad = j >> 4, l15 = j & 15;
    int jj = wave * 16 + l15;

    // ===== phase 0: scatter (782 chunks) || weight transpose (5) || x-pack (196) =====
    for (int u = blockIdx.x; u < P0_UNITS; u += GRID) {
        if (u < SCHUNKS) {
            int base = u * 512;
            if (t < NBUCK) s_ia[t] = 0;
            __syncthreads();
            int pkA[4], bkA[4], lrA[4]; bool vA = false;
            int pkB[4], bkB[4], lrB[4]; bool vB = false;
            {
                int i = base + t;
                if (i < E4) {
                    vA = true;
                    int4 s4 = ((const int4*)esrc)[i];
                    int4 d4 = ((const int4*)edst)[i];
                    bkA[0] = d4.x >> 8; pkA[0] = ((d4.x & 255) << 16) | s4.x; lrA[0] = atomicAdd(&s_ia[bkA[0]], 1);
                    bkA[1] = d4.y >> 8; pkA[1] = ((d4.y & 255) << 16) | s4.y; lrA[1] = atomicAdd(&s_ia[bkA[1]], 1);
                    bkA[2] = d4.z >> 8; pkA[2] = ((d4.z & 255) << 16) | s4.z; lrA[2] = atomicAdd(&s_ia[bkA[2]], 1);
                    bkA[3] = d4.w >> 8; pkA[3] = ((d4.w & 255) << 16) | s4.w; lrA[3] = atomicAdd(&s_ia[bkA[3]], 1);
                }
            }
            {
                int i = base + 256 + t;
                if (i < E4) {
                    vB = true;
                    int4 s4 = ((const int4*)esrc)[i];
                    int4 d4 = ((const int4*)edst)[i];
                    bkB[0] = d4.x >> 8; pkB[0] = ((d4.x & 255) << 16) | s4.x; lrB[0] = atomicAdd(&s_ia[bkB[0]], 1);
                    bkB[1] = d4.y >> 8; pkB[1] = ((d4.y & 255) << 16) | s4.y; lrB[1] = atomicAdd(&s_ia[bkB[1]], 1);
                    bkB[2] = d4.z >> 8; pkB[2] = ((d4.z & 255) << 16) | s4.z; lrB[2] = atomicAdd(&s_ia[bkB[2]], 1);
                    bkB[3] = d4.w >> 8; pkB[3] = ((d4.w & 255) << 16) | s4.w; lrB[3] = atomicAdd(&s_ia[bkB[3]], 1);
                }
            }
            __syncthreads();
            if (t < NBUCK) {
                int c = s_ia[t];
                s_ia[t] = c ? atomicAdd(&gcnt[t], c) : 0;
            }
            __syncthreads();
            if (vA) {
#pragma unroll
                for (int q = 0; q < 4; q++) gpacked[bkA[q] * BUCKCAP + s_ia[bkA[q]] + lrA[q]] = pkA[q];
            }
            if (vB) {
#pragma unroll
                for (int q = 0; q < 4; q++) gpacked[bkB[q] * BUCKCAP + s_ia[bkB[q]] + lrB[q]] = pkB[q];
            }
            __syncthreads();
        } else if (u < SCHUNKS + 5) {
            int b = u - SCHUNKS;
            const float* w = (b == 0) ? w2_0f : (b == 1) ? w1_1f : (b == 2) ? w2_1f
                             : (b == 3) ? w1_2f : w2_2f;
            unsigned short* ow = wt + b * (H * H);
            for (int idx = t; idx < H * H; idx += 256) {
                int k = idx >> 6, jc = idx & 63;
                ow[jc * H + k] = (unsigned short)bf16_rne(w[idx]);
            }
        } else {
            int node = (u - SCHUNKS - 5) * 256 + t;
            if (node < N_NODES) {
                uint2 p;
                p.x = bf16_rne(x[node * 3 + 0]) | (bf16_rne(x[node * 3 + 1]) << 16);
                p.y = bf16_rne(x[node * 3 + 2]);
                xb[node] = p;
            }
        }
    }
    gbar(bar);

    // ===== phase 1: per-bucket local CSR (blocks 0..195) =====
    if (blockIdx.x == 0 && t == 0) row_start[N_NODES] = N_EDGES;
    if (blockIdx.x < NBUCK) {
        int b = blockIdx.x;
        int v = (t < NBUCK) ? gcnt[t] : 0;
        s_ib[t] = v;
        __syncthreads();
        for (int off = 1; off < 256; off <<= 1) {
            int u2 = 0;
            if (t >= off) u2 = s_ib[t - off];
            __syncthreads();
            if (t >= off) s_ib[t] += u2;
            __syncthreads();
        }
        int bs = (b > 0) ? s_ib[b - 1] : 0;
        int cnt_b = gcnt[b];
        const int* gp = gpacked + (size_t)b * BUCKCAP;
        s_ia[t] = 0;
        __syncthreads();
        for (int i = t; i < cnt_b; i += 256) atomicAdd(&s_ia[gp[i] >> 16], 1);
        __syncthreads();
        int c = s_ia[t];
        s_ib[t] = c;
        __syncthreads();
        for (int off = 1; off < 256; off <<= 1) {
            int u2 = 0;
            if (t >= off) u2 = s_ib[t - off];
            __syncthreads();
            if (t >= off) s_ib[t] += u2;
            __syncthreads();
        }
        int excl = s_ib[t] - c;
        int node = b * 256 + t;
        if (node < N_NODES) row_start[node] = bs + excl;
        s_ia[t] = excl;
        __syncthreads();
        for (int i = t; i < cnt_b; i += 256) {
            int p = gp[i];
            int pos = atomicAdd(&s_ia[p >> 16], 1);
            edge_src[bs + pos] = p & 0xffff;
        }
    }
    gbar(bar);

    // ===== phase 2: layer 1 =====
    {
        const unsigned short* w2t_0 = wt;
        float wj0 = w1_0[j], wj1 = w1_0[H + j], wj2 = w1_0[2 * H + j];
        float sc1 = rsqrtf(v_0[j] + BN_EPS) * g_0[j];
        float sh1 = bb_0[j] - m_0[j] * sc1;
        float bj = b1_0[j];
        short8 wb20 = *(const short8*)&w2t_0[jj * H + quad * 8];
        short8 wb21 = *(const short8*)&w2t_0[jj * H + quad * 8 + 32];
        float bb2 = b2_0[jj];
        for (int grp = blockIdx.x; grp < NGROUP; grp += GRID)
            gin1_group(grp * 16, wave, j, quad, l15, jj, x, xb, row_start, edge_src,
                       wj0, wj1, wj2, sc1, sh1, bj, wb20, wb21, bb2,
                       s_xs, s_mid, s_bat, batch, pool, h1);
    }
    gbar(bar);

    // ===== phase 3: layer 2 =====
    {
        const unsigned short* w1t = wt + 1 * H * H;
        const unsigned short* w2t = wt + 2 * H * H;
        float sc = rsqrtf(v_1[jj] + BN_EPS) * g_1[jj];
        float sh = bb_1[jj] - m_1[jj] * sc;
        float bb1 = b1_1[jj], bb2 = b2_1[jj];
        short8 wb10 = *(const short8*)&w1t[jj * H + quad * 8];
        short8 wb11 = *(const short8*)&w1t[jj * H + quad * 8 + 32];
        short8 wb20 = *(const short8*)&w2t[jj * H + quad * 8];
        short8 wb21 = *(const short8*)&w2t[jj * H + quad * 8 + 32];
        for (int grp = blockIdx.x; grp < NGROUP; grp += GRID)
            gin_group(grp * 16, wave, j, quad, l15, jj, (const char*)h1, row_start, edge_src,
                      wb10, wb11, wb20, wb21, sc, sh, bb1, bb2,
                      s_xs, s_mid, s_bat, batch, pool + 64, h2);
    }
    gbar(bar);

    // ===== phase 4: layer 3 =====
    {
        const unsigned short* w1t = wt + 3 * H * H;
        const unsigned short* w2t = wt + 4 * H * H;
        float sc = rsqrtf(v_2[jj] + BN_EPS) * g_2[jj];
        float sh = bb_2[jj] - m_2[jj] * sc;
        float bb1 = b1_2[jj], bb2 = b2_2[jj];
        short8 wb10 = *(const short8*)&w1t[jj * H + quad * 8];
        short8 wb11 = *(const short8*)&w1t[jj * H + quad * 8 + 32];
        short8 wb20 = *(const short8*)&w2t[jj * H + quad * 8];
        short8 wb21 = *(const short8*)&w2t[jj * H + quad * 8 + 32];
        for (int grp = blockIdx.x; grp < NGROUP; grp += GRID)
            gin_group(grp * 16, wave, j, quad, l15, jj, (const char*)h2, row_start, edge_src,
                      wb10, wb11, wb20, wb21, sc, sh, bb1, bb2,
                      s_xs, s_mid, s_bat, batch, pool + 128, h3);
    }
    gbar(bar);

    // ===== phase 5: head (one graph per block) =====
    for (int g = blockIdx.x; g < G_GRAPHS; g += GRID) {
        if (t < 3 * H) s_hr[t] = pool[g * 192 + t];
        __syncthreads();
        if (t < 3 * H) {
            float acc = lin1_b[t];
            for (int k = 0; k < 3 * H; k++) acc += s_hr[k] * lin1_w[k * (3 * H) + t];
            s_hm[t] = fmaxf(acc, 0.f);
        }
        __syncthreads();
        if (t < C_CLS) {
            float z = lin2_b[t];
            for (int k = 0; k < 3 * H; k++) z += s_hm[k] * lin2_w[k * C_CLS + t];
            s_z[t] = z;
        }
        __syncthreads();
        if (t < C_CLS) {
            float z0 = s_z[0], z1 = s_z[1];
            float mx = fmaxf(z0, z1);
            float lse = mx + logf(expf(z0 - mx) + expf(z1 - mx));
            out[g * C_CLS + t] = s_z[t];
            out[G_GRAPHS * C_CLS + g * C_CLS + t] = s_z[t] - lse;
        }
        __syncthreads();
    }
}

extern "C" void kernel_launch(void* const* d_in, const int* in_sizes, int n_in,
                              void* d_out, int out_size, void* d_ws, size_t ws_size,
                              hipStream_t stream) {
    const float* x = (const float*)d_in[0];
    const float* cw1[3], *cb1[3], *cg[3], *cbb[3], *cm[3], *cv[3], *cw2[3], *cb2[3];
    for (int l = 0; l < 3; l++) {
        int b = 1 + 8 * l;
        cw1[l] = (const float*)d_in[b + 0];
        cb1[l] = (const float*)d_in[b + 1];
        cg[l]  = (const float*)d_in[b + 2];
        cbb[l] = (const float*)d_in[b + 3];
        cm[l]  = (const float*)d_in[b + 4];
        cv[l]  = (const float*)d_in[b + 5];
        cw2[l] = (const float*)d_in[b + 6];
        cb2[l] = (const float*)d_in[b + 7];
    }
    const float* lin1_w = (const float*)d_in[25];
    const float* lin1_b = (const float*)d_in[26];
    const float* lin2_w = (const float*)d_in[27];
    const float* lin2_b = (const float*)d_in[28];
    const int* edge_index = (const int*)d_in[29];
    const int* batch = (const int*)d_in[30];
    const int* esrc = edge_index;
    const int* edst = edge_index + N_EDGES;
    float* out = (float*)d_out;

    // workspace layout (gcnt, bar, pool contiguous -> single memset)
    int* edge_src = (int*)d_ws;                      // E
    int* gpacked = edge_src + N_EDGES;               // NBUCK*BUCKCAP
    int* gcnt = gpacked + (size_t)NBUCK * BUCKCAP;   // NBUCK
    int* bar = gcnt + NBUCK;                         // 2
    float* pool = (float*)(bar + 2);                 // G*192
    int* row_start = (int*)(pool + G_GRAPHS * 3 * H);// N+2
    uintptr_t hp = (uintptr_t)(row_start + N_NODES + 2);
    hp = (hp + 127) & ~(uintptr_t)127;
    unsigned short* wt = (unsigned short*)hp;        // 5 * H*H bf16
    uint2* xb = (uint2*)(wt + 5 * H * H);            // N
    __hip_bfloat16* h1 = (__hip_bfloat16*)(xb + N_NODES);
    __hip_bfloat16* h2 = h1 + (size_t)N_NODES * H;
    __hip_bfloat16* h3 = h2 + (size_t)N_NODES * H;

    hipMemsetAsync(gcnt, 0,
                   (NBUCK + 2) * sizeof(int) + (size_t)G_GRAPHS * 3 * H * sizeof(float),
                   stream);
    mega_kernel<<<GRID, 256, 0, stream>>>(
        x,
        cw1[0], cb1[0], cg[0], cbb[0], cm[0], cv[0], cw2[0], cb2[0],
        cw1[1], cb1[1], cg[1], cbb[1], cm[1], cv[1], cw2[1], cb2[1],
        cw1[2], cb1[2], cg[2], cbb[2], cm[2], cv[2], cw2[2], cb2[2],
        lin1_w, lin1_b, lin2_w, lin2_b,
        esrc, edst, batch,
        edge_src, gpacked, gcnt, bar, pool, row_start,
        wt, xb, h1, h2, h3, out);
}

// Round 3
// 314.295 us; speedup vs baseline: 2.8658x; 2.8658x over previous
//
#include <hip/hip_runtime.h>
#include <hip/hip_bf16.h>
#include <math.h>

#define N_NODES 50000
#define N_EDGES 1600000
#define H 64
#define G_GRAPHS 512
#define C_CLS 2
#define BN_EPS 1e-5f
#define NBUCK 196           // buckets of 256 nodes: dst>>8 in [0,196)
#define BUCKCAP 16384
#define E4 (N_EDGES / 4)    // 400000
#define SCHUNKS ((E4 + 511) / 512)        // 782 scatter chunks
#define XCHUNKS ((N_NODES + 255) / 256)   // 196
#define IOP 72              // padded LDS row stride (bf16)
#define ZROW N_NODES        // zero-row sentinel index (row 50000 of h buffers)
#define HSTRIDE ((N_NODES + 1) * H)

typedef __attribute__((ext_vector_type(8))) short short8;
typedef __attribute__((ext_vector_type(4))) float floatx4;

__device__ __forceinline__ float bflo(unsigned int u) { return __uint_as_float(u << 16); }
__device__ __forceinline__ float bfhi(unsigned int u) { return __uint_as_float(u & 0xffff0000u); }
__device__ __forceinline__ unsigned int bf16_rne(float f) {
    unsigned int u = __float_as_uint(f);
    u += 0x7fffu + ((u >> 16) & 1u);
    return u >> 16;
}

#define RED3(A) { A += __shfl_xor(A, 8); A += __shfl_xor(A, 16); A += __shfl_xor(A, 32); }
#define RED6(A) { A += __shfl_xor(A, 1); A += __shfl_xor(A, 2); A += __shfl_xor(A, 4); \
                  A += __shfl_xor(A, 8); A += __shfl_xor(A, 16); A += __shfl_xor(A, 32); }

// ---------- fused prep + scatter: blocks [0,782) scatter, [782,787) wT, [787,983) x-pack, 983 zero-rows ----------
__global__ __launch_bounds__(256) void prepscatter_kernel(
    const int* __restrict__ src, const int* __restrict__ dst,
    int* __restrict__ gcnt, int* __restrict__ gpacked,
    const float* __restrict__ w2_0, const float* __restrict__ w1_1,
    const float* __restrict__ w2_1, const float* __restrict__ w1_2,
    const float* __restrict__ w2_2, unsigned short* __restrict__ wt,
    const float* __restrict__ x, uint2* __restrict__ xb,
    __hip_bfloat16* __restrict__ h1, __hip_bfloat16* __restrict__ h2) {
    int b = blockIdx.x, t = threadIdx.x;
    if (b < SCHUNKS) {
        __shared__ int bh[NBUCK];
        if (t < NBUCK) bh[t] = 0;
        __syncthreads();
        int base = b * 512;
        int pkA[4], bkA[4], lrA[4]; bool vA = false;
        int pkB[4], bkB[4], lrB[4]; bool vB = false;
        {
            int i = base + t;
            if (i < E4) {
                vA = true;
                int4 s4 = ((const int4*)src)[i];
                int4 d4 = ((const int4*)dst)[i];
                bkA[0] = d4.x >> 8; pkA[0] = ((d4.x & 255) << 16) | s4.x; lrA[0] = atomicAdd(&bh[bkA[0]], 1);
                bkA[1] = d4.y >> 8; pkA[1] = ((d4.y & 255) << 16) | s4.y; lrA[1] = atomicAdd(&bh[bkA[1]], 1);
                bkA[2] = d4.z >> 8; pkA[2] = ((d4.z & 255) << 16) | s4.z; lrA[2] = atomicAdd(&bh[bkA[2]], 1);
                bkA[3] = d4.w >> 8; pkA[3] = ((d4.w & 255) << 16) | s4.w; lrA[3] = atomicAdd(&bh[bkA[3]], 1);
            }
        }
        {
            int i = base + 256 + t;
            if (i < E4) {
                vB = true;
                int4 s4 = ((const int4*)src)[i];
                int4 d4 = ((const int4*)dst)[i];
                bkB[0] = d4.x >> 8; pkB[0] = ((d4.x & 255) << 16) | s4.x; lrB[0] = atomicAdd(&bh[bkB[0]], 1);
                bkB[1] = d4.y >> 8; pkB[1] = ((d4.y & 255) << 16) | s4.y; lrB[1] = atomicAdd(&bh[bkB[1]], 1);
                bkB[2] = d4.z >> 8; pkB[2] = ((d4.z & 255) << 16) | s4.z; lrB[2] = atomicAdd(&bh[bkB[2]], 1);
                bkB[3] = d4.w >> 8; pkB[3] = ((d4.w & 255) << 16) | s4.w; lrB[3] = atomicAdd(&bh[bkB[3]], 1);
            }
        }
        __syncthreads();
        if (t < NBUCK) {
            int c = bh[t];
            bh[t] = c ? atomicAdd(&gcnt[t], c) : 0;
        }
        __syncthreads();
        if (vA) {
#pragma unroll
            for (int q = 0; q < 4; q++) gpacked[bkA[q] * BUCKCAP + bh[bkA[q]] + lrA[q]] = pkA[q];
        }
        if (vB) {
#pragma unroll
            for (int q = 0; q < 4; q++) gpacked[bkB[q] * BUCKCAP + bh[bkB[q]] + lrB[q]] = pkB[q];
        }
    } else if (b < SCHUNKS + 5) {
        int w_id = b - SCHUNKS;
        const float* w = (w_id == 0) ? w2_0 : (w_id == 1) ? w1_1 : (w_id == 2) ? w2_1
                         : (w_id == 3) ? w1_2 : w2_2;
        unsigned short* o = wt + w_id * (H * H);
        for (int idx = t; idx < H * H; idx += 256) {
            int k = idx >> 6, jc = idx & 63;
            o[jc * H + k] = (unsigned short)bf16_rne(w[idx]);
        }
    } else if (b < SCHUNKS + 5 + XCHUNKS) {
        int node = (b - SCHUNKS - 5) * 256 + t;
        if (node < N_NODES) {
            uint2 p;
            p.x = bf16_rne(x[node * 3 + 0]) | (bf16_rne(x[node * 3 + 1]) << 16);
            p.y = bf16_rne(x[node * 3 + 2]);
            xb[node] = p;
        }
    } else {
        // zero-row sentinels for h1, h2 (row index ZROW = 50000), 128 B each
        uint4 z = {0u, 0u, 0u, 0u};
        if (t < 8) ((uint4*)((unsigned short*)h1 + (size_t)ZROW * H))[t] = z;
        else if (t < 16) ((uint4*)((unsigned short*)h2 + (size_t)ZROW * H))[t - 8] = z;
    }
}

// ---------- CSR pass 2: per-bucket local CSR ----------
__global__ __launch_bounds__(256) void bcsr_kernel(const int* __restrict__ gpacked,
                                                   const int* __restrict__ gcnt,
                                                   int* __restrict__ row_start,
                                                   int* __restrict__ edge_src) {
    __shared__ int cnt[256];
    __shared__ int pref[256];
    int b = blockIdx.x;
    int t = threadIdx.x;

    int v = (t < NBUCK) ? gcnt[t] : 0;
    pref[t] = v;
    __syncthreads();
    for (int off = 1; off < 256; off <<= 1) {
        int u = 0;
        if (t >= off) u = pref[t - off];
        __syncthreads();
        if (t >= off) pref[t] += u;
        __syncthreads();
    }
    int bs = (b > 0) ? pref[b - 1] : 0;
    int cnt_b = gcnt[b];
    if (b == 0 && t == 0) row_start[N_NODES] = N_EDGES;
    __syncthreads();

    const int* gp = gpacked + (size_t)b * BUCKCAP;
    cnt[t] = 0;
    __syncthreads();
    for (int i = t; i < cnt_b; i += 256) atomicAdd(&cnt[gp[i] >> 16], 1);
    __syncthreads();
    int c = cnt[t];
    pref[t] = c;
    __syncthreads();
    for (int off = 1; off < 256; off <<= 1) {
        int u = 0;
        if (t >= off) u = pref[t - off];
        __syncthreads();
        if (t >= off) pref[t] += u;
        __syncthreads();
    }
    int excl = pref[t] - c;
    int node = b * 256 + t;
    if (node < N_NODES) row_start[node] = bs + excl;
    cnt[t] = excl;
    __syncthreads();
    for (int i = t; i < cnt_b; i += 256) {
        int p = gp[i];
        int pos = atomicAdd(&cnt[p >> 16], 1);
        edge_src[bs + pos] = p & 0xffff;
    }
}

// ---------- layer 1 fused: strided gather, 4-wave MFMA lin2, pooled ----------
__global__ __launch_bounds__(512) void gin1_fused16_kernel(
    const float* __restrict__ x, const uint2* __restrict__ xb,
    const int* __restrict__ row_start, const int* __restrict__ edge_src,
    const float* __restrict__ w1, const float* __restrict__ b1,
    const float* __restrict__ bn_g, const float* __restrict__ bn_b,
    const float* __restrict__ bn_m, const float* __restrict__ bn_v,
    const unsigned short* __restrict__ w2t, const float* __restrict__ b2,
    __hip_bfloat16* __restrict__ hout, const int* __restrict__ batch,
    float* __restrict__ pool) {
    __shared__ unsigned short s_mid[16 * IOP];
    __shared__ unsigned short s_xs[16 * IOP];
    __shared__ int s_bat[16];

    int tid = threadIdx.x;
    int wave = tid >> 6, j = tid & 63;
    int quad = j >> 4, l15 = j & 15;
    int nodebase = blockIdx.x * 16;     // 3125 blocks x 16 = 50000 exact
    if (tid < 16) s_bat[tid] = batch[nodebase + tid];

    float wj0 = w1[j], wj1 = w1[H + j], wj2 = w1[2 * H + j];
    float sc = rsqrtf(bn_v[j] + BN_EPS) * bn_g[j];
    float sh = bn_b[j] - bn_m[j] * sc;
    float bj = b1[j];

    // phase A: each wave gathers+lin1 its 2 nodes
    for (int nl = wave * 2; nl < wave * 2 + 2; nl++) {
        int node = nodebase + nl;
        int rs = row_start[node], re = row_start[node + 1];
        float a0 = 0.f, a1 = 0.f, a2 = 0.f;
        for (int t2 = rs + j; t2 < re; t2 += 64) {
            uint2 p = xb[edge_src[t2]];
            a0 += bflo(p.x); a1 += bfhi(p.x); a2 += bflo(p.y);
        }
        RED6(a0) RED6(a1) RED6(a2)
        float in0 = a0 + x[node * 3 + 0];
        float in1 = a1 + x[node * 3 + 1];
        float in2 = a2 + x[node * 3 + 2];
        float m = bj + in0 * wj0 + in1 * wj1 + in2 * wj2;
        m = fmaxf(m * sc + sh, 0.f);
        s_mid[nl * IOP + j] = (unsigned short)bf16_rne(m);
    }
    __syncthreads();

    // phase B: waves 0-3, jt = wave: out = relu(mid@w2+b2); pool atomics
    if (wave < 4) {
        int jj = wave * 16 + l15;
        float bb2 = b2[jj];
        short8 m0 = *(const short8*)&s_mid[l15 * IOP + quad * 8];
        short8 m1 = *(const short8*)&s_mid[l15 * IOP + quad * 8 + 32];
        short8 b0 = *(const short8*)&w2t[jj * H + quad * 8];
        short8 bv = *(const short8*)&w2t[jj * H + quad * 8 + 32];
        floatx4 c = {0.f, 0.f, 0.f, 0.f};
        c = __builtin_amdgcn_mfma_f32_16x16x32_bf16(m0, b0, c, 0, 0, 0);
        c = __builtin_amdgcn_mfma_f32_16x16x32_bf16(m1, bv, c, 0, 0, 0);
        float vv[4];
#pragma unroll
        for (int r = 0; r < 4; r++) {
            vv[r] = fmaxf(c[r] + bb2, 0.f);
            s_xs[(quad * 4 + r) * IOP + jj] = (unsigned short)bf16_rne(vv[r]);
        }
        int bq0 = s_bat[quad * 4], bq3 = s_bat[quad * 4 + 3];
        if (bq0 == bq3) {
            atomicAdd(&pool[bq0 * 192 + jj], (vv[0] + vv[1]) + (vv[2] + vv[3]));
        } else {
            atomicAdd(&pool[s_bat[quad * 4 + 0] * 192 + jj], vv[0]);
            atomicAdd(&pool[s_bat[quad * 4 + 1] * 192 + jj], vv[1]);
            atomicAdd(&pool[s_bat[quad * 4 + 2] * 192 + jj], vv[2]);
            atomicAdd(&pool[s_bat[quad * 4 + 3] * 192 + jj], vv[3]);
        }
    }
    __syncthreads();

    if (wave < 2) {
        int r = wave * 8 + (j >> 3);
        short8 v = *(const short8*)&s_xs[r * IOP + (j & 7) * 8];
        *(short8*)((unsigned short*)hout + (size_t)(nodebase + r) * H + (j & 7) * 8) = v;
    }
}

#define ACCA(R) { \
    a0 += bflo(R.x); a1 += bfhi(R.x); a2 += bflo(R.y); a3 += bfhi(R.y); \
    a4 += bflo(R.z); a5 += bfhi(R.z); a6 += bflo(R.w); a7 += bfhi(R.w); }
#define ACCB(R) { \
    b0 += bflo(R.x); b1 += bfhi(R.x); b2 += bflo(R.y); b3 += bfhi(R.y); \
    b4 += bflo(R.z); b5 += bfhi(R.z); b6 += bflo(R.w); b7 += bfhi(R.w); }

// ---------- layers 2/3: zero-row-padded unconditional gather, A/B interleaved, 4-wave MLP ----------
__global__ __launch_bounds__(512, 4) void gin_fused16_kernel(
    const __hip_bfloat16* __restrict__ hin, const int* __restrict__ row_start,
    const int* __restrict__ edge_src,
    const unsigned short* __restrict__ w1t, const float* __restrict__ b1,
    const float* __restrict__ bn_g, const float* __restrict__ bn_b,
    const float* __restrict__ bn_m, const float* __restrict__ bn_v,
    const unsigned short* __restrict__ w2t, const float* __restrict__ b2,
    __hip_bfloat16* __restrict__ hout, const int* __restrict__ batch,
    float* __restrict__ pool) {
    __shared__ unsigned short s_xs[16 * IOP];
    __shared__ unsigned short s_mid[16 * IOP];
    __shared__ int s_bat[16];

    int tid = threadIdx.x;
    int wave = tid >> 6, j = tid & 63;
    int o = j >> 3, jo = j & 7;
    int quad = j >> 4, l15 = j & 15;
    int nodebase = blockIdx.x * 16;
    if (tid < 16) s_bat[tid] = batch[nodebase + tid];

    const char* hb = (const char*)hin;

    // phase A: wave's 2 nodes (A,B) gathered with interleaved unconditional loads.
    // Out-of-range edge slots read the zero row (ZROW) -> contribute exact 0.
    int n0 = nodebase + wave * 2;
    int rsA = row_start[n0];
    int rsB = row_start[n0 + 1];
    int reB = row_start[n0 + 2];
    int cntA = rsB - rsA, cntB = reB - rsB;
    int cmax = max(cntA, cntB);

    float a0 = 0.f, a1 = 0.f, a2 = 0.f, a3 = 0.f, a4 = 0.f, a5 = 0.f, a6 = 0.f, a7 = 0.f;
    float b0 = 0.f, b1v = 0.f, b2v = 0.f, b3 = 0.f, b4 = 0.f, b5 = 0.f, b6 = 0.f, b7 = 0.f;
#define b1 b1v
#define b2 b2v
    for (int base = 0; base < cmax; base += 64) {
        int svA = (base + j < cntA) ? edge_src[rsA + base + j] : ZROW;
        int svB = (base + j < cntB) ? edge_src[rsB + base + j] : ZROW;
#pragma unroll
        for (int g = 0; g < 64; g += 32) {
            bool doA = (base + g) < cntA;   // wave-uniform group skip
            bool doB = (base + g) < cntB;
            uint4 RA0, RA1, RA2, RA3, RB0, RB1, RB2, RB3;
            if (doA) {
                int s0 = __shfl(svA, g + o);
                int s1 = __shfl(svA, g + 8 + o);
                int s2 = __shfl(svA, g + 16 + o);
                int s3 = __shfl(svA, g + 24 + o);
                RA0 = *(const uint4*)(hb + (size_t)s0 * 128 + jo * 16);
                RA1 = *(const uint4*)(hb + (size_t)s1 * 128 + jo * 16);
                RA2 = *(const uint4*)(hb + (size_t)s2 * 128 + jo * 16);
                RA3 = *(const uint4*)(hb + (size_t)s3 * 128 + jo * 16);
            }
            if (doB) {
                int s0 = __shfl(svB, g + o);
                int s1 = __shfl(svB, g + 8 + o);
                int s2 = __shfl(svB, g + 16 + o);
                int s3 = __shfl(svB, g + 24 + o);
                RB0 = *(const uint4*)(hb + (size_t)s0 * 128 + jo * 16);
                RB1 = *(const uint4*)(hb + (size_t)s1 * 128 + jo * 16);
                RB2 = *(const uint4*)(hb + (size_t)s2 * 128 + jo * 16);
                RB3 = *(const uint4*)(hb + (size_t)s3 * 128 + jo * 16);
            }
            if (doA) { ACCA(RA0) ACCA(RA1) ACCA(RA2) ACCA(RA3) }
            if (doB) { ACCB(RB0) ACCB(RB1) ACCB(RB2) ACCB(RB3) }
        }
    }
#undef b1
#undef b2
    // independent butterfly reductions over the octet dim (A and B chains interleave)
    RED3(a0) RED3(b0) RED3(a1) RED3(b1v) RED3(a2) RED3(b2v) RED3(a3) RED3(b3)
    RED3(a4) RED3(b4) RED3(a5) RED3(b5) RED3(a6) RED3(b6) RED3(a7) RED3(b7)

    if (o < 2) {
        int nl = wave * 2 + o;
        float r0 = (o == 0) ? a0 : b0, r1 = (o == 0) ? a1 : b1v;
        float r2 = (o == 0) ? a2 : b2v, r3 = (o == 0) ? a3 : b3;
        float r4 = (o == 0) ? a4 : b4, r5 = (o == 0) ? a5 : b5;
        float r6 = (o == 0) ? a6 : b6, r7 = (o == 0) ? a7 : b7;
        uint4 raw = *(const uint4*)(hb + (size_t)(nodebase + nl) * 128 + jo * 16);
        r0 += bflo(raw.x); r1 += bfhi(raw.x);
        r2 += bflo(raw.y); r3 += bfhi(raw.y);
        r4 += bflo(raw.z); r5 += bfhi(raw.z);
        r6 += bflo(raw.w); r7 += bfhi(raw.w);
        uint4 ov;
        ov.x = bf16_rne(r0) | (bf16_rne(r1) << 16);
        ov.y = bf16_rne(r2) | (bf16_rne(r3) << 16);
        ov.z = bf16_rne(r4) | (bf16_rne(r5) << 16);
        ov.w = bf16_rne(r6) | (bf16_rne(r7) << 16);
        *(uint4*)&s_xs[nl * IOP + jo * 8] = ov;
    }
    __syncthreads();

    // phase B: waves 0-3, jt = wave: full MLP for all 16 nodes
    if (wave < 4) {
        int jj = wave * 16 + l15;
        float scv = rsqrtf(bn_v[jj] + BN_EPS) * bn_g[jj];
        float shv = bn_b[jj] - bn_m[jj] * scv;
        float bb1 = b1[jj], bb2 = b2[jj];
        short8 A0 = *(const short8*)&s_xs[l15 * IOP + quad * 8];
        short8 A1 = *(const short8*)&s_xs[l15 * IOP + quad * 8 + 32];
        short8 w10 = *(const short8*)&w1t[jj * H + quad * 8];
        short8 w11 = *(const short8*)&w1t[jj * H + quad * 8 + 32];
        floatx4 c = {0.f, 0.f, 0.f, 0.f};
        c = __builtin_amdgcn_mfma_f32_16x16x32_bf16(A0, w10, c, 0, 0, 0);
        c = __builtin_amdgcn_mfma_f32_16x16x32_bf16(A1, w11, c, 0, 0, 0);
#pragma unroll
        for (int r = 0; r < 4; r++) {
            float v = (c[r] + bb1) * scv + shv;
            v = fmaxf(v, 0.f);
            s_mid[(quad * 4 + r) * IOP + jj] = (unsigned short)bf16_rne(v);
        }
        __syncthreads();
        short8 M0 = *(const short8*)&s_mid[l15 * IOP + quad * 8];
        short8 M1 = *(const short8*)&s_mid[l15 * IOP + quad * 8 + 32];
        short8 w20 = *(const short8*)&w2t[jj * H + quad * 8];
        short8 w21 = *(const short8*)&w2t[jj * H + quad * 8 + 32];
        floatx4 c2 = {0.f, 0.f, 0.f, 0.f};
        c2 = __builtin_amdgcn_mfma_f32_16x16x32_bf16(M0, w20, c2, 0, 0, 0);
        c2 = __builtin_amdgcn_mfma_f32_16x16x32_bf16(M1, w21, c2, 0, 0, 0);
        float vv[4];
#pragma unroll
        for (int r = 0; r < 4; r++) {
            vv[r] = fmaxf(c2[r] + bb2, 0.f);
            s_xs[(quad * 4 + r) * IOP + jj] = (unsigned short)bf16_rne(vv[r]);
        }
        int bq0 = s_bat[quad * 4], bq3 = s_bat[quad * 4 + 3];
        if (bq0 == bq3) {
            atomicAdd(&pool[bq0 * 192 + jj], (vv[0] + vv[1]) + (vv[2] + vv[3]));
        } else {
            atomicAdd(&pool[s_bat[quad * 4 + 0] * 192 + jj], vv[0]);
            atomicAdd(&pool[s_bat[quad * 4 + 1] * 192 + jj], vv[1]);
            atomicAdd(&pool[s_bat[quad * 4 + 2] * 192 + jj], vv[2]);
            atomicAdd(&pool[s_bat[quad * 4 + 3] * 192 + jj], vv[3]);
        }
    } else {
        __syncthreads();   // match phase-B internal barrier
    }
    __syncthreads();

    if (wave < 2) {
        int r = wave * 8 + (j >> 3);
        short8 v = *(const short8*)&s_xs[r * IOP + (j & 7) * 8];
        *(short8*)((unsigned short*)hout + (size_t)(nodebase + r) * H + (j & 7) * 8) = v;
    }
}

// ---------- head: pooled rows already in pool[]; tiny MLP + log_softmax ----------
__global__ __launch_bounds__(192) void head_kernel(
    const float* __restrict__ pool,
    const float* __restrict__ lin1_w, const float* __restrict__ lin1_b,
    const float* __restrict__ lin2_w, const float* __restrict__ lin2_b,
    float* __restrict__ out) {
    __shared__ float s_row[3 * H];
    __shared__ float s_mid[3 * H];
    __shared__ float s_z[C_CLS];

    int g = blockIdx.x;
    int j = threadIdx.x;
    s_row[j] = pool[g * 192 + j];
    __syncthreads();

    float acc = lin1_b[j];
    for (int k = 0; k < 3 * H; k++) acc += s_row[k] * lin1_w[k * (3 * H) + j];
    s_mid[j] = fmaxf(acc, 0.f);
    __syncthreads();

    if (j < C_CLS) {
        float z = lin2_b[j];
        for (int k = 0; k < 3 * H; k++) z += s_mid[k] * lin2_w[k * C_CLS + j];
        s_z[j] = z;
    }
    __syncthreads();
    if (j < C_CLS) {
        float z0 = s_z[0], z1 = s_z[1];
        float mx = fmaxf(z0, z1);
        float lse = mx + logf(expf(z0 - mx) + expf(z1 - mx));
        out[g * C_CLS + j] = s_z[j];
        out[G_GRAPHS * C_CLS + g * C_CLS + j] = s_z[j] - lse;
    }
}

extern "C" void kernel_launch(void* const* d_in, const int* in_sizes, int n_in,
                              void* d_out, int out_size, void* d_ws, size_t ws_size,
                              hipStream_t stream) {
    const float* x = (const float*)d_in[0];
    const float* cw1[3], *cb1[3], *cg[3], *cbb[3], *cm[3], *cv[3], *cw2[3], *cb2[3];
    for (int l = 0; l < 3; l++) {
        int b = 1 + 8 * l;
        cw1[l] = (const float*)d_in[b + 0];
        cb1[l] = (const float*)d_in[b + 1];
        cg[l]  = (const float*)d_in[b + 2];
        cbb[l] = (const float*)d_in[b + 3];
        cm[l]  = (const float*)d_in[b + 4];
        cv[l]  = (const float*)d_in[b + 5];
        cw2[l] = (const float*)d_in[b + 6];
        cb2[l] = (const float*)d_in[b + 7];
    }
    const float* lin1_w = (const float*)d_in[25];
    const float* lin1_b = (const float*)d_in[26];
    const float* lin2_w = (const float*)d_in[27];
    const float* lin2_b = (const float*)d_in[28];
    const int* edge_index = (const int*)d_in[29];
    const int* batch = (const int*)d_in[30];
    const int* src = edge_index;
    const int* dst = edge_index + N_EDGES;
    float* out = (float*)d_out;

    // workspace layout (gcnt, pool contiguous -> single memset)
    int* edge_src = (int*)d_ws;                      // E
    int* gpacked = edge_src + N_EDGES;               // NBUCK*BUCKCAP
    int* gcnt = gpacked + (size_t)NBUCK * BUCKCAP;   // NBUCK
    float* pool = (float*)(gcnt + NBUCK);            // G*192
    int* row_start = (int*)(pool + G_GRAPHS * 3 * H);// N+2
    uintptr_t hp = (uintptr_t)(row_start + N_NODES + 2);
    hp = (hp + 127) & ~(uintptr_t)127;
    unsigned short* wt = (unsigned short*)hp;        // 5 * H*H bf16
    uint2* xb = (uint2*)(wt + 5 * H * H);            // N
    __hip_bfloat16* h1 = (__hip_bfloat16*)(xb + N_NODES);  // (N+1)*H each (zero row at N)
    __hip_bfloat16* h2 = h1 + (size_t)HSTRIDE;
    __hip_bfloat16* h3 = h2 + (size_t)HSTRIDE;

    const unsigned short* w2t_0 = wt + 0 * H * H;
    const unsigned short* w1t_1 = wt + 1 * H * H;
    const unsigned short* w2t_1 = wt + 2 * H * H;
    const unsigned short* w1t_2 = wt + 3 * H * H;
    const unsigned short* w2t_2 = wt + 4 * H * H;

    hipMemsetAsync(gcnt, 0, NBUCK * sizeof(int) + (size_t)G_GRAPHS * 3 * H * sizeof(float),
                   stream);
    prepscatter_kernel<<<SCHUNKS + 5 + XCHUNKS + 1, 256, 0, stream>>>(
        src, dst, gcnt, gpacked, cw2[0], cw1[1], cw2[1], cw1[2], cw2[2], wt, x, xb, h1, h2);
    bcsr_kernel<<<NBUCK, 256, 0, stream>>>(gpacked, gcnt, row_start, edge_src);

    const int fgrid = N_NODES / 16;   // 3125, exact

    gin1_fused16_kernel<<<fgrid, 512, 0, stream>>>(x, xb, row_start, edge_src,
        cw1[0], cb1[0], cg[0], cbb[0], cm[0], cv[0], w2t_0, cb2[0], h1, batch, pool);
    gin_fused16_kernel<<<fgrid, 512, 0, stream>>>(h1, row_start, edge_src,
        w1t_1, cb1[1], cg[1], cbb[1], cm[1], cv[1], w2t_1, cb2[1], h2, batch, pool + 64);
    gin_fused16_kernel<<<fgrid, 512, 0, stream>>>(h2, row_start, edge_src,
        w1t_2, cb1[2], cg[2], cbb[2], cm[2], cv[2], w2t_2, cb2[2], h3, batch, pool + 128);
    head_kernel<<<G_GRAPHS, 3 * H, 0, stream>>>(pool,
        lin1_w, lin1_b, lin2_w, lin2_b, out);
}

// Round 4
// 308.697 us; speedup vs baseline: 2.9177x; 1.0181x over previous
//
#include <hip/hip_runtime.h>
#include <hip/hip_bf16.h>
#include <math.h>

#define N_NODES 50000
#define N_EDGES 1600000
#define H 64
#define G_GRAPHS 512
#define C_CLS 2
#define BN_EPS 1e-5f
#define NBUCK 196           // buckets of 256 nodes: dst>>8 in [0,196)
#define BUCKCAP 16384
#define E4 (N_EDGES / 4)    // 400000
#define SCHUNKS ((E4 + 511) / 512)        // 782 scatter chunks
#define XCHUNKS ((N_NODES + 255) / 256)   // 196
#define IOP 72              // padded LDS row stride (bf16)
#define ZROW N_NODES        // zero-row sentinel index (row 50000 of h buffers)
#define HSTRIDE ((N_NODES + 1) * H)

typedef __attribute__((ext_vector_type(8))) short short8;
typedef __attribute__((ext_vector_type(4))) float floatx4;

__device__ __forceinline__ float bflo(unsigned int u) { return __uint_as_float(u << 16); }
__device__ __forceinline__ float bfhi(unsigned int u) { return __uint_as_float(u & 0xffff0000u); }
__device__ __forceinline__ unsigned int bf16_rne(float f) {
    unsigned int u = __float_as_uint(f);
    u += 0x7fffu + ((u >> 16) & 1u);
    return u >> 16;
}

#define RED3(A) { A += __shfl_xor(A, 8); A += __shfl_xor(A, 16); A += __shfl_xor(A, 32); }
#define RED6(A) { A += __shfl_xor(A, 1); A += __shfl_xor(A, 2); A += __shfl_xor(A, 4); \
                  A += __shfl_xor(A, 8); A += __shfl_xor(A, 16); A += __shfl_xor(A, 32); }

// ---------- fused prep + scatter ----------
__global__ __launch_bounds__(256) void prepscatter_kernel(
    const int* __restrict__ src, const int* __restrict__ dst,
    int* __restrict__ gcnt, int* __restrict__ gpacked,
    const float* __restrict__ w2_0, const float* __restrict__ w1_1,
    const float* __restrict__ w2_1, const float* __restrict__ w1_2,
    const float* __restrict__ w2_2, unsigned short* __restrict__ wt,
    const float* __restrict__ x, uint2* __restrict__ xb,
    __hip_bfloat16* __restrict__ h1, __hip_bfloat16* __restrict__ h2) {
    int b = blockIdx.x, t = threadIdx.x;
    if (b < SCHUNKS) {
        __shared__ int bh[NBUCK];
        if (t < NBUCK) bh[t] = 0;
        __syncthreads();
        int base = b * 512;
        int pkA[4], bkA[4], lrA[4]; bool vA = false;
        int pkB[4], bkB[4], lrB[4]; bool vB = false;
        {
            int i = base + t;
            if (i < E4) {
                vA = true;
                int4 s4 = ((const int4*)src)[i];
                int4 d4 = ((const int4*)dst)[i];
                bkA[0] = d4.x >> 8; pkA[0] = ((d4.x & 255) << 16) | s4.x; lrA[0] = atomicAdd(&bh[bkA[0]], 1);
                bkA[1] = d4.y >> 8; pkA[1] = ((d4.y & 255) << 16) | s4.y; lrA[1] = atomicAdd(&bh[bkA[1]], 1);
                bkA[2] = d4.z >> 8; pkA[2] = ((d4.z & 255) << 16) | s4.z; lrA[2] = atomicAdd(&bh[bkA[2]], 1);
                bkA[3] = d4.w >> 8; pkA[3] = ((d4.w & 255) << 16) | s4.w; lrA[3] = atomicAdd(&bh[bkA[3]], 1);
            }
        }
        {
            int i = base + 256 + t;
            if (i < E4) {
                vB = true;
                int4 s4 = ((const int4*)src)[i];
                int4 d4 = ((const int4*)dst)[i];
                bkB[0] = d4.x >> 8; pkB[0] = ((d4.x & 255) << 16) | s4.x; lrB[0] = atomicAdd(&bh[bkB[0]], 1);
                bkB[1] = d4.y >> 8; pkB[1] = ((d4.y & 255) << 16) | s4.y; lrB[1] = atomicAdd(&bh[bkB[1]], 1);
                bkB[2] = d4.z >> 8; pkB[2] = ((d4.z & 255) << 16) | s4.z; lrB[2] = atomicAdd(&bh[bkB[2]], 1);
                bkB[3] = d4.w >> 8; pkB[3] = ((d4.w & 255) << 16) | s4.w; lrB[3] = atomicAdd(&bh[bkB[3]], 1);
            }
        }
        __syncthreads();
        if (t < NBUCK) {
            int c = bh[t];
            bh[t] = c ? atomicAdd(&gcnt[t], c) : 0;
        }
        __syncthreads();
        if (vA) {
#pragma unroll
            for (int q = 0; q < 4; q++) gpacked[bkA[q] * BUCKCAP + bh[bkA[q]] + lrA[q]] = pkA[q];
        }
        if (vB) {
#pragma unroll
            for (int q = 0; q < 4; q++) gpacked[bkB[q] * BUCKCAP + bh[bkB[q]] + lrB[q]] = pkB[q];
        }
    } else if (b < SCHUNKS + 5) {
        int w_id = b - SCHUNKS;
        const float* w = (w_id == 0) ? w2_0 : (w_id == 1) ? w1_1 : (w_id == 2) ? w2_1
                         : (w_id == 3) ? w1_2 : w2_2;
        unsigned short* o = wt + w_id * (H * H);
        for (int idx = t; idx < H * H; idx += 256) {
            int k = idx >> 6, jc = idx & 63;
            o[jc * H + k] = (unsigned short)bf16_rne(w[idx]);
        }
    } else if (b < SCHUNKS + 5 + XCHUNKS) {
        int node = (b - SCHUNKS - 5) * 256 + t;
        if (node < N_NODES) {
            uint2 p;
            p.x = bf16_rne(x[node * 3 + 0]) | (bf16_rne(x[node * 3 + 1]) << 16);
            p.y = bf16_rne(x[node * 3 + 2]);
            xb[node] = p;
        }
    } else {
        // zero-row sentinels for h1, h2 (row index ZROW = 50000), 128 B each
        uint4 z = {0u, 0u, 0u, 0u};
        if (t < 8) ((uint4*)((unsigned short*)h1 + (size_t)ZROW * H))[t] = z;
        else if (t < 16) ((uint4*)((unsigned short*)h2 + (size_t)ZROW * H))[t - 8] = z;
    }
}

// ---------- CSR pass 2: per-bucket local CSR ----------
__global__ __launch_bounds__(256) void bcsr_kernel(const int* __restrict__ gpacked,
                                                   const int* __restrict__ gcnt,
                                                   int* __restrict__ row_start,
                                                   int* __restrict__ edge_src) {
    __shared__ int cnt[256];
    __shared__ int pref[256];
    int b = blockIdx.x;
    int t = threadIdx.x;

    int v = (t < NBUCK) ? gcnt[t] : 0;
    pref[t] = v;
    __syncthreads();
    for (int off = 1; off < 256; off <<= 1) {
        int u = 0;
        if (t >= off) u = pref[t - off];
        __syncthreads();
        if (t >= off) pref[t] += u;
        __syncthreads();
    }
    int bs = (b > 0) ? pref[b - 1] : 0;
    int cnt_b = gcnt[b];
    if (b == 0 && t == 0) row_start[N_NODES] = N_EDGES;
    __syncthreads();

    const int* gp = gpacked + (size_t)b * BUCKCAP;
    cnt[t] = 0;
    __syncthreads();
    for (int i = t; i < cnt_b; i += 256) atomicAdd(&cnt[gp[i] >> 16], 1);
    __syncthreads();
    int c = cnt[t];
    pref[t] = c;
    __syncthreads();
    for (int off = 1; off < 256; off <<= 1) {
        int u = 0;
        if (t >= off) u = pref[t - off];
        __syncthreads();
        if (t >= off) pref[t] += u;
        __syncthreads();
    }
    int excl = pref[t] - c;
    int node = b * 256 + t;
    if (node < N_NODES) row_start[node] = bs + excl;
    cnt[t] = excl;
    __syncthreads();
    for (int i = t; i < cnt_b; i += 256) {
        int p = gp[i];
        int pos = atomicAdd(&cnt[p >> 16], 1);
        edge_src[bs + pos] = p & 0xffff;
    }
}

// ---------- layer 1 fused: strided gather, 4-wave MFMA lin2, pooled ----------
__global__ __launch_bounds__(512) void gin1_fused16_kernel(
    const float* __restrict__ x, const uint2* __restrict__ xb,
    const int* __restrict__ row_start, const int* __restrict__ edge_src,
    const float* __restrict__ w1, const float* __restrict__ b1,
    const float* __restrict__ bn_g, const float* __restrict__ bn_b,
    const float* __restrict__ bn_m, const float* __restrict__ bn_v,
    const unsigned short* __restrict__ w2t, const float* __restrict__ b2,
    __hip_bfloat16* __restrict__ hout, const int* __restrict__ batch,
    float* __restrict__ pool) {
    __shared__ unsigned short s_mid[16 * IOP];
    __shared__ unsigned short s_xs[16 * IOP];
    __shared__ int s_bat[16];

    int tid = threadIdx.x;
    int wave = tid >> 6, j = tid & 63;
    int quad = j >> 4, l15 = j & 15;
    int nodebase = blockIdx.x * 16;
    if (tid < 16) s_bat[tid] = batch[nodebase + tid];

    float wj0 = w1[j], wj1 = w1[H + j], wj2 = w1[2 * H + j];
    float sc = rsqrtf(bn_v[j] + BN_EPS) * bn_g[j];
    float sh = bn_b[j] - bn_m[j] * sc;
    float bj = b1[j];

    // phase A: each wave gathers+lin1 its 2 nodes
    for (int nl = wave * 2; nl < wave * 2 + 2; nl++) {
        int node = nodebase + nl;
        int rs = row_start[node], re = row_start[node + 1];
        float a0 = 0.f, a1 = 0.f, a2 = 0.f;
        for (int t2 = rs + j; t2 < re; t2 += 64) {
            uint2 p = xb[edge_src[t2]];
            a0 += bflo(p.x); a1 += bfhi(p.x); a2 += bflo(p.y);
        }
        RED6(a0) RED6(a1) RED6(a2)
        float in0 = a0 + x[node * 3 + 0];
        float in1 = a1 + x[node * 3 + 1];
        float in2 = a2 + x[node * 3 + 2];
        float m = bj + in0 * wj0 + in1 * wj1 + in2 * wj2;
        m = fmaxf(m * sc + sh, 0.f);
        s_mid[nl * IOP + j] = (unsigned short)bf16_rne(m);
    }
    __syncthreads();

    // phase B: waves 0-3, jt = wave: out = relu(mid@w2+b2); pool atomics
    if (wave < 4) {
        int jj = wave * 16 + l15;
        float bb2 = b2[jj];
        short8 m0 = *(const short8*)&s_mid[l15 * IOP + quad * 8];
        short8 m1 = *(const short8*)&s_mid[l15 * IOP + quad * 8 + 32];
        short8 b0 = *(const short8*)&w2t[jj * H + quad * 8];
        short8 bv = *(const short8*)&w2t[jj * H + quad * 8 + 32];
        floatx4 c = {0.f, 0.f, 0.f, 0.f};
        c = __builtin_amdgcn_mfma_f32_16x16x32_bf16(m0, b0, c, 0, 0, 0);
        c = __builtin_amdgcn_mfma_f32_16x16x32_bf16(m1, bv, c, 0, 0, 0);
        float vv[4];
#pragma unroll
        for (int r = 0; r < 4; r++) {
            vv[r] = fmaxf(c[r] + bb2, 0.f);
            s_xs[(quad * 4 + r) * IOP + jj] = (unsigned short)bf16_rne(vv[r]);
        }
        int bq0 = s_bat[quad * 4], bq3 = s_bat[quad * 4 + 3];
        if (bq0 == bq3) {
            atomicAdd(&pool[bq0 * 192 + jj], (vv[0] + vv[1]) + (vv[2] + vv[3]));
        } else {
            atomicAdd(&pool[s_bat[quad * 4 + 0] * 192 + jj], vv[0]);
            atomicAdd(&pool[s_bat[quad * 4 + 1] * 192 + jj], vv[1]);
            atomicAdd(&pool[s_bat[quad * 4 + 2] * 192 + jj], vv[2]);
            atomicAdd(&pool[s_bat[quad * 4 + 3] * 192 + jj], vv[3]);
        }
    }
    __syncthreads();

    if (wave < 2) {
        int r = wave * 8 + (j >> 3);
        short8 v = *(const short8*)&s_xs[r * IOP + (j & 7) * 8];
        *(short8*)((unsigned short*)hout + (size_t)(nodebase + r) * H + (j & 7) * 8) = v;
    }
}

#define ACCA(R) { \
    a0 += bflo(R.x); a1 += bfhi(R.x); a2 += bflo(R.y); a3 += bfhi(R.y); \
    a4 += bflo(R.z); a5 += bfhi(R.z); a6 += bflo(R.w); a7 += bfhi(R.w); }
#define ACCB(R) { \
    c0 += bflo(R.x); c1 += bfhi(R.x); c2 += bflo(R.y); c3 += bfhi(R.y); \
    c4 += bflo(R.z); c5 += bfhi(R.z); c6 += bflo(R.w); c7 += bfhi(R.w); }

// ---------- layers 2/3: 8-granular gated gather (sentinel tail), A/B interleaved, 4-wave MLP ----------
__global__ __launch_bounds__(512) void gin_fused16_kernel(
    const __hip_bfloat16* __restrict__ hin, const int* __restrict__ row_start,
    const int* __restrict__ edge_src,
    const unsigned short* __restrict__ w1t, const float* __restrict__ b1,
    const float* __restrict__ bn_g, const float* __restrict__ bn_b,
    const float* __restrict__ bn_m, const float* __restrict__ bn_v,
    const unsigned short* __restrict__ w2t, const float* __restrict__ b2,
    __hip_bfloat16* __restrict__ hout, const int* __restrict__ batch,
    float* __restrict__ pool) {
    __shared__ unsigned short s_xs[16 * IOP];
    __shared__ unsigned short s_mid[16 * IOP];
    __shared__ int s_bat[16];

    int tid = threadIdx.x;
    int wave = tid >> 6, j = tid & 63;
    int o = j >> 3, jo = j & 7;
    int quad = j >> 4, l15 = j & 15;
    int nodebase = blockIdx.x * 16;
    if (tid < 16) s_bat[tid] = batch[nodebase + tid];

    const char* hb = (const char*)hin;

    // phase A: wave's 2 nodes (A,B). Row-groups of 8 edges gated wave-uniformly;
    // within a live group, out-of-range lanes read the zero row (exact +0).
    int n0 = nodebase + wave * 2;
    int rsA = row_start[n0];
    int rsB = row_start[n0 + 1];
    int reB = row_start[n0 + 2];
    int cntA = rsB - rsA, cntB = reB - rsB;
    int cmax = max(cntA, cntB);

    float a0 = 0.f, a1 = 0.f, a2 = 0.f, a3 = 0.f, a4 = 0.f, a5 = 0.f, a6 = 0.f, a7 = 0.f;
    float c0 = 0.f, c1 = 0.f, c2 = 0.f, c3 = 0.f, c4 = 0.f, c5 = 0.f, c6 = 0.f, c7 = 0.f;

    for (int base = 0; base < cmax; base += 64) {
        int iA = base + j;
        int svA = (iA < cntA) ? edge_src[rsA + iA] : ZROW;
        int svB = (iA < cntB) ? edge_src[rsB + iA] : ZROW;
#pragma unroll
        for (int k = 0; k < 64; k += 16) {
            bool dA0 = (base + k) < cntA, dA1 = (base + k + 8) < cntA;
            bool dB0 = (base + k) < cntB, dB1 = (base + k + 8) < cntB;
            uint4 RA0, RA1, RB0, RB1;
            if (dA0) {
                int s = __shfl(svA, k + o);
                RA0 = *(const uint4*)(hb + (size_t)s * 128 + jo * 16);
            }
            if (dA1) {
                int s = __shfl(svA, k + 8 + o);
                RA1 = *(const uint4*)(hb + (size_t)s * 128 + jo * 16);
            }
            if (dB0) {
                int s = __shfl(svB, k + o);
                RB0 = *(const uint4*)(hb + (size_t)s * 128 + jo * 16);
            }
            if (dB1) {
                int s = __shfl(svB, k + 8 + o);
                RB1 = *(const uint4*)(hb + (size_t)s * 128 + jo * 16);
            }
            if (dA0) ACCA(RA0)
            if (dA1) ACCA(RA1)
            if (dB0) ACCB(RB0)
            if (dB1) ACCB(RB1)
        }
    }
    // butterfly over the octet dim (A and B chains interleave)
    RED3(a0) RED3(c0) RED3(a1) RED3(c1) RED3(a2) RED3(c2) RED3(a3) RED3(c3)
    RED3(a4) RED3(c4) RED3(a5) RED3(c5) RED3(a6) RED3(c6) RED3(a7) RED3(c7)

    if (o < 2) {
        int nl = wave * 2 + o;
        float r0 = (o == 0) ? a0 : c0, r1 = (o == 0) ? a1 : c1;
        float r2 = (o == 0) ? a2 : c2, r3 = (o == 0) ? a3 : c3;
        float r4 = (o == 0) ? a4 : c4, r5 = (o == 0) ? a5 : c5;
        float r6 = (o == 0) ? a6 : c6, r7 = (o == 0) ? a7 : c7;
        uint4 raw = *(const uint4*)(hb + (size_t)(nodebase + nl) * 128 + jo * 16);
        r0 += bflo(raw.x); r1 += bfhi(raw.x);
        r2 += bflo(raw.y); r3 += bfhi(raw.y);
        r4 += bflo(raw.z); r5 += bfhi(raw.z);
        r6 += bflo(raw.w); r7 += bfhi(raw.w);
        uint4 ov;
        ov.x = bf16_rne(r0) | (bf16_rne(r1) << 16);
        ov.y = bf16_rne(r2) | (bf16_rne(r3) << 16);
        ov.z = bf16_rne(r4) | (bf16_rne(r5) << 16);
        ov.w = bf16_rne(r6) | (bf16_rne(r7) << 16);
        *(uint4*)&s_xs[nl * IOP + jo * 8] = ov;
    }
    __syncthreads();

    // phase B, GEMM1 (waves 0-3, jt = wave): mid = relu(bn(xs @ w1 + b1))
    int jj = (wave & 3) * 16 + l15;
    float scv, shv, bb1, bb2;
    if (wave < 4) {
        scv = rsqrtf(bn_v[jj] + BN_EPS) * bn_g[jj];
        shv = bn_b[jj] - bn_m[jj] * scv;
        bb1 = b1[jj];
        bb2 = b2[jj];
        short8 A0 = *(const short8*)&s_xs[l15 * IOP + quad * 8];
        short8 A1 = *(const short8*)&s_xs[l15 * IOP + quad * 8 + 32];
        short8 w10 = *(const short8*)&w1t[jj * H + quad * 8];
        short8 w11 = *(const short8*)&w1t[jj * H + quad * 8 + 32];
        floatx4 c = {0.f, 0.f, 0.f, 0.f};
        c = __builtin_amdgcn_mfma_f32_16x16x32_bf16(A0, w10, c, 0, 0, 0);
        c = __builtin_amdgcn_mfma_f32_16x16x32_bf16(A1, w11, c, 0, 0, 0);
#pragma unroll
        for (int r = 0; r < 4; r++) {
            float v = (c[r] + bb1) * scv + shv;
            v = fmaxf(v, 0.f);
            s_mid[(quad * 4 + r) * IOP + jj] = (unsigned short)bf16_rne(v);
        }
    }
    __syncthreads();

    // phase B, GEMM2: out = relu(mid @ w2 + b2); pool atomics
    if (wave < 4) {
        short8 M0 = *(const short8*)&s_mid[l15 * IOP + quad * 8];
        short8 M1 = *(const short8*)&s_mid[l15 * IOP + quad * 8 + 32];
        short8 w20 = *(const short8*)&w2t[jj * H + quad * 8];
        short8 w21 = *(const short8*)&w2t[jj * H + quad * 8 + 32];
        floatx4 c2 = {0.f, 0.f, 0.f, 0.f};
        c2 = __builtin_amdgcn_mfma_f32_16x16x32_bf16(M0, w20, c2, 0, 0, 0);
        c2 = __builtin_amdgcn_mfma_f32_16x16x32_bf16(M1, w21, c2, 0, 0, 0);
        float vv[4];
#pragma unroll
        for (int r = 0; r < 4; r++) {
            vv[r] = fmaxf(c2[r] + bb2, 0.f);
            s_xs[(quad * 4 + r) * IOP + jj] = (unsigned short)bf16_rne(vv[r]);
        }
        int bq0 = s_bat[quad * 4], bq3 = s_bat[quad * 4 + 3];
        if (bq0 == bq3) {
            atomicAdd(&pool[bq0 * 192 + jj], (vv[0] + vv[1]) + (vv[2] + vv[3]));
        } else {
            atomicAdd(&pool[s_bat[quad * 4 + 0] * 192 + jj], vv[0]);
            atomicAdd(&pool[s_bat[quad * 4 + 1] * 192 + jj], vv[1]);
            atomicAdd(&pool[s_bat[quad * 4 + 2] * 192 + jj], vv[2]);
            atomicAdd(&pool[s_bat[quad * 4 + 3] * 192 + jj], vv[3]);
        }
    }
    __syncthreads();

    if (wave < 2) {
        int r = wave * 8 + (j >> 3);
        short8 v = *(const short8*)&s_xs[r * IOP + (j & 7) * 8];
        *(short8*)((unsigned short*)hout + (size_t)(nodebase + r) * H + (j & 7) * 8) = v;
    }
}

// ---------- head ----------
__global__ __launch_bounds__(192) void head_kernel(
    const float* __restrict__ pool,
    const float* __restrict__ lin1_w, const float* __restrict__ lin1_b,
    const float* __restrict__ lin2_w, const float* __restrict__ lin2_b,
    float* __restrict__ out) {
    __shared__ float s_row[3 * H];
    __shared__ float s_mid[3 * H];
    __shared__ float s_z[C_CLS];

    int g = blockIdx.x;
    int j = threadIdx.x;
    s_row[j] = pool[g * 192 + j];
    __syncthreads();

    float acc = lin1_b[j];
    for (int k = 0; k < 3 * H; k++) acc += s_row[k] * lin1_w[k * (3 * H) + j];
    s_mid[j] = fmaxf(acc, 0.f);
    __syncthreads();

    if (j < C_CLS) {
        float z = lin2_b[j];
        for (int k = 0; k < 3 * H; k++) z += s_mid[k] * lin2_w[k * C_CLS + j];
        s_z[j] = z;
    }
    __syncthreads();
    if (j < C_CLS) {
        float z0 = s_z[0], z1 = s_z[1];
        float mx = fmaxf(z0, z1);
        float lse = mx + logf(expf(z0 - mx) + expf(z1 - mx));
        out[g * C_CLS + j] = s_z[j];
        out[G_GRAPHS * C_CLS + g * C_CLS + j] = s_z[j] - lse;
    }
}

extern "C" void kernel_launch(void* const* d_in, const int* in_sizes, int n_in,
                              void* d_out, int out_size, void* d_ws, size_t ws_size,
                              hipStream_t stream) {
    const float* x = (const float*)d_in[0];
    const float* cw1[3], *cb1[3], *cg[3], *cbb[3], *cm[3], *cv[3], *cw2[3], *cb2[3];
    for (int l = 0; l < 3; l++) {
        int b = 1 + 8 * l;
        cw1[l] = (const float*)d_in[b + 0];
        cb1[l] = (const float*)d_in[b + 1];
        cg[l]  = (const float*)d_in[b + 2];
        cbb[l] = (const float*)d_in[b + 3];
        cm[l]  = (const float*)d_in[b + 4];
        cv[l]  = (const float*)d_in[b + 5];
        cw2[l] = (const float*)d_in[b + 6];
        cb2[l] = (const float*)d_in[b + 7];
    }
    const float* lin1_w = (const float*)d_in[25];
    const float* lin1_b = (const float*)d_in[26];
    const float* lin2_w = (const float*)d_in[27];
    const float* lin2_b = (const float*)d_in[28];
    const int* edge_index = (const int*)d_in[29];
    const int* batch = (const int*)d_in[30];
    const int* src = edge_index;
    const int* dst = edge_index + N_EDGES;
    float* out = (float*)d_out;

    // workspace layout (gcnt, pool contiguous -> single memset)
    int* edge_src = (int*)d_ws;                      // E
    int* gpacked = edge_src + N_EDGES;               // NBUCK*BUCKCAP
    int* gcnt = gpacked + (size_t)NBUCK * BUCKCAP;   // NBUCK
    float* pool = (float*)(gcnt + NBUCK);            // G*192
    int* row_start = (int*)(pool + G_GRAPHS * 3 * H);// N+2
    uintptr_t hp = (uintptr_t)(row_start + N_NODES + 2);
    hp = (hp + 127) & ~(uintptr_t)127;
    unsigned short* wt = (unsigned short*)hp;        // 5 * H*H bf16
    uint2* xb = (uint2*)(wt + 5 * H * H);            // N
    __hip_bfloat16* h1 = (__hip_bfloat16*)(xb + N_NODES);  // (N+1)*H each (zero row at N)
    __hip_bfloat16* h2 = h1 + (size_t)HSTRIDE;
    __hip_bfloat16* h3 = h2 + (size_t)HSTRIDE;

    const unsigned short* w2t_0 = wt + 0 * H * H;
    const unsigned short* w1t_1 = wt + 1 * H * H;
    const unsigned short* w2t_1 = wt + 2 * H * H;
    const unsigned short* w1t_2 = wt + 3 * H * H;
    const unsigned short* w2t_2 = wt + 4 * H * H;

    hipMemsetAsync(gcnt, 0, NBUCK * sizeof(int) + (size_t)G_GRAPHS * 3 * H * sizeof(float),
                   stream);
    prepscatter_kernel<<<SCHUNKS + 5 + XCHUNKS + 1, 256, 0, stream>>>(
        src, dst, gcnt, gpacked, cw2[0], cw1[1], cw2[1], cw1[2], cw2[2], wt, x, xb, h1, h2);
    bcsr_kernel<<<NBUCK, 256, 0, stream>>>(gpacked, gcnt, row_start, edge_src);

    const int fgrid = N_NODES / 16;   // 3125, exact

    gin1_fused16_kernel<<<fgrid, 512, 0, stream>>>(x, xb, row_start, edge_src,
        cw1[0], cb1[0], cg[0], cbb[0], cm[0], cv[0], w2t_0, cb2[0], h1, batch, pool);
    gin_fused16_kernel<<<fgrid, 512, 0, stream>>>(h1, row_start, edge_src,
        w1t_1, cb1[1], cg[1], cbb[1], cm[1], cv[1], w2t_1, cb2[1], h2, batch, pool + 64);
    gin_fused16_kernel<<<fgrid, 512, 0, stream>>>(h2, row_start, edge_src,
        w1t_2, cb1[2], cg[2], cbb[2], cm[2], cv[2], w2t_2, cb2[2], h3, batch, pool + 128);
    head_kernel<<<G_GRAPHS, 3 * H, 0, stream>>>(pool,
        lin1_w, lin1_b, lin2_w, lin2_b, out);
}